// Round 1
// baseline (888.379 us; speedup 1.0000x reference)
//
#include <hip/hip_runtime.h>
#include <math.h>

// Problem constants
#define BB 64
#define CCH 64
#define LL 8192
#define NN 3
#define FF 4097
#define FP 4104   // padded row stride for spectra (16B-aligned rows)
#define HIDC 128
#define M4 4096

// ---------------------------------------------------------------------------
// Stockham radix-2 complex FFT, length 4096, in LDS. 256 threads.
// dir = +1.0f : forward (e^{-2pi i pk/n});  dir = -1.0f : positive-sign (for inverse)
// Input in sa; output ends in sa (12 stages, even number of buffer swaps).
// ---------------------------------------------------------------------------
__device__ __forceinline__ void fft4096_sh(float2* sa, float2* sb, int tid, float dir)
{
    float2* src = sa;
    float2* dst = sb;
    int ncur = 4096;
    for (int st = 0; st < 12; ++st) {
        int s = 1 << st;
        float inv = dir * (-6.283185307179586f) / (float)ncur;
        for (int i = tid; i < 2048; i += 256) {
            int p = i >> st;
            int q = i & (s - 1);
            float ang = inv * (float)p;
            float sw, cw;
            __sincosf(ang, &sw, &cw);
            float2 u = src[i];          // q + s*p == i
            float2 v = src[i + 2048];   // q + s*(p+m)
            float2 sm = make_float2(u.x + v.x, u.y + v.y);
            float2 df = make_float2(u.x - v.x, u.y - v.y);
            float2 tw = make_float2(df.x * cw - df.y * sw, df.x * sw + df.y * cw);
            int o = q + (p << (st + 1));
            dst[o] = sm;
            dst[o + s] = tw;
        }
        __syncthreads();
        float2* t = src; src = dst; dst = t;
        ncur >>= 1;
    }
}

// ---------------------------------------------------------------------------
// Kernel A: rfft of each (b,c) row, ortho norm. Writes fxr/fxi [B*C][FP].
// ---------------------------------------------------------------------------
__global__ __launch_bounds__(256) void k_rfft(const float* __restrict__ x,
                                              float* __restrict__ fxr,
                                              float* __restrict__ fxi)
{
    __shared__ float2 sa[4096];
    __shared__ float2 sb[4096];
    int bc = blockIdx.x;
    int tid = threadIdx.x;
    const float2* xr = (const float2*)(x + (size_t)bc * LL);
    for (int j = tid; j < 4096; j += 256) sa[j] = xr[j];
    __syncthreads();
    fft4096_sh(sa, sb, tid, 1.0f);

    const float scale = 0.011048543456039806f; // 1/sqrt(8192)
    size_t row = (size_t)bc * FP;
    for (int it = 0; it < 8; ++it) {
        int k = tid + 256 * it;   // 0..2047
        if (k == 0) {
            float2 z0 = sa[0];
            fxr[row + 0]  = (z0.x + z0.y) * scale;
            fxi[row + 0]  = 0.0f;
            fxr[row + M4] = (z0.x - z0.y) * scale;
            fxi[row + M4] = 0.0f;
            float2 zh = sa[2048];           // X[M/2] = conj(Z[M/2])
            fxr[row + 2048] =  zh.x * scale;
            fxi[row + 2048] = -zh.y * scale;
        } else {
            float2 zk = sa[k];
            float2 zm = sa[M4 - k];
            float er = 0.5f * (zk.x + zm.x);
            float ei = 0.5f * (zk.y - zm.y);
            float dr = 0.5f * (zk.x - zm.x);
            float di = 0.5f * (zk.y + zm.y);
            float sp, cp;
            __sincosf(6.283185307179586f * (float)k * (1.0f / 8192.0f), &sp, &cp);
            // X[k] = E + e^{-i phi} * O,  O = -i*D
            fxr[row + k] = (er + cp * di - sp * dr) * scale;
            fxi[row + k] = (ei - cp * dr - sp * di) * scale;
            // X[M-k] = conj(E) - e^{+i phi} * conj(O)
            fxr[row + M4 - k] = (er - (cp * di - sp * dr)) * scale;
            fxi[row + M4 - k] = (-ei - (cp * dr + sp * di)) * scale;
        }
    }
}

// ---------------------------------------------------------------------------
// Kernel B1: conv1 (C=64 -> HID=128, k=3, SAME) + bias + SELU + partial sums
// over t, per 128-wide t tile. Also captures y1[t=0] and y1[t=F-1] endpoints.
// grid: (33 tiles, 64 b, 2 enc); block 256 = 16 tx * 16 ty; 8h x 8t per thread
// ---------------------------------------------------------------------------
__global__ __launch_bounds__(256) void k_conv1(const float* __restrict__ fxr,
                                               const float* __restrict__ fxi,
                                               const float* __restrict__ wR1,
                                               const float* __restrict__ bR1,
                                               const float* __restrict__ wI1,
                                               const float* __restrict__ bI1,
                                               float* __restrict__ part,
                                               float* __restrict__ e0,
                                               float* __restrict__ e1)
{
    __shared__ float smem[64 * 132];
    int tile = blockIdx.x;   // 0..32
    int b    = blockIdx.y;   // 0..63
    int enc  = blockIdx.z;   // 0:R 1:I
    const float* src = enc ? fxi : fxr;
    const float* w1  = enc ? wI1 : wR1;
    const float* b1  = enc ? bI1 : bR1;
    int tid = threadIdx.x;
    int tx = tid & 15;
    int ty = tid >> 4;
    int t0 = tile * 128;

    const float* xb = src + (size_t)b * 64 * FP;
    for (int ii = tid; ii < 64 * 130; ii += 256) {
        int c  = ii / 130;
        int tt = ii - c * 130;
        int tg = t0 - 1 + tt;
        float v = (tg >= 0 && tg < FF) ? xb[(size_t)c * FP + tg] : 0.0f;
        smem[c * 132 + tt] = v;
    }
    __syncthreads();

    float acc[8][8];
#pragma unroll
    for (int j = 0; j < 8; ++j)
#pragma unroll
        for (int u = 0; u < 8; ++u) acc[j][u] = 0.0f;

    int hbase = ty * 8;
    for (int c = 0; c < 64; ++c) {
        float xv[10];
#pragma unroll
        for (int u = 0; u < 10; ++u) xv[u] = smem[c * 132 + tx * 8 + u];
#pragma unroll
        for (int j = 0; j < 8; ++j) {
            const float* wp = w1 + ((hbase + j) * 64 + c) * 3;
            float w0 = wp[0], w1v = wp[1], w2v = wp[2];
#pragma unroll
            for (int u = 0; u < 8; ++u)
                acc[j][u] += w0 * xv[u] + w1v * xv[u + 1] + w2v * xv[u + 2];
        }
    }

    const float SELU_S = 1.0507009873554805f;
    const float SELU_A = 1.6732632423543772f;
    float psum[8];
    int ebase = (enc * 64 + b) * 128;
#pragma unroll
    for (int j = 0; j < 8; ++j) {
        float bias = b1[hbase + j];
        float sumj = 0.0f;
#pragma unroll
        for (int u = 0; u < 8; ++u) {
            int tg = t0 + tx * 8 + u;
            if (tg < FF) {
                float v = acc[j][u] + bias;
                float y = SELU_S * (v > 0.0f ? v : SELU_A * (__expf(v) - 1.0f));
                sumj += y;
                if (tg == 0)      e0[ebase + hbase + j] = y;
                if (tg == FF - 1) e1[ebase + hbase + j] = y;
            }
        }
        psum[j] = sumj;
    }
    __syncthreads();   // done reading smem; reuse as reduction buffer
#pragma unroll
    for (int j = 0; j < 8; ++j) smem[(hbase + j) * 16 + tx] = psum[j];
    __syncthreads();
    if (tid < 128) {
        int h = tid;
        float s = 0.0f;
#pragma unroll
        for (int q = 0; q < 16; ++q) s += smem[h * 16 + q];
        part[((size_t)(enc * 64 + b) * 128 + h) * 33 + tile] = s;
    }
}

// ---------------------------------------------------------------------------
// Kernel B2: conv2 (fused with mean via endpoint algebra) + bias + softmax
// grid: (64 b, 2 enc), 128 threads (one per h)
// ---------------------------------------------------------------------------
__global__ __launch_bounds__(128) void k_head(const float* __restrict__ part,
                                              const float* __restrict__ e0,
                                              const float* __restrict__ e1,
                                              const float* __restrict__ wR2,
                                              const float* __restrict__ bR2,
                                              const float* __restrict__ wI2,
                                              const float* __restrict__ bI2,
                                              float* __restrict__ Cw)
{
    __shared__ float red[3][128];
    int b   = blockIdx.x;
    int enc = blockIdx.y;
    const float* w2 = enc ? wI2 : wR2;
    const float* b2 = enc ? bI2 : bR2;
    int h = threadIdx.x;
    size_t pb = ((size_t)(enc * 64 + b) * 128 + h) * 33;
    float T = 0.0f;
    for (int t = 0; t < 33; ++t) T += part[pb + t];
    float e0v = e0[(enc * 64 + b) * 128 + h];
    float e1v = e1[(enc * 64 + b) * 128 + h];
#pragma unroll
    for (int n = 0; n < 3; ++n) {
        const float* wp = w2 + (n * 128 + h) * 3;
        // mean over t of SAME conv:  w0*(T-e_last) + w1*T + w2*(T-e_first)
        red[n][h] = wp[0] * (T - e1v) + wp[1] * T + wp[2] * (T - e0v);
    }
    __syncthreads();
    if (h == 0) {
        float lg[3];
        for (int n = 0; n < 3; ++n) {
            float s = 0.0f;
            for (int q = 0; q < 128; ++q) s += red[n][q];
            lg[n] = b2[n] + s / 4097.0f;
        }
        float mx = fmaxf(lg[0], fmaxf(lg[1], lg[2]));
        float ex0 = __expf(lg[0] - mx);
        float ex1 = __expf(lg[1] - mx);
        float ex2 = __expf(lg[2] - mx);
        float den = ex0 + ex1 + ex2;
        Cw[(enc * 64 + b) * 3 + 0] = ex0 / den;
        Cw[(enc * 64 + b) * 3 + 1] = ex1 / den;
        Cw[(enc * 64 + b) * 3 + 2] = ex2 / den;
    }
}

// ---------------------------------------------------------------------------
// Kernel C: P = fx * Kf (Kf from filter bank + softmax coeffs), then irfft
// via length-4096 positive-sign FFT. One block per (b,c) row.
// ---------------------------------------------------------------------------
__global__ __launch_bounds__(256) void k_irfft(const float* __restrict__ fxr,
                                               const float* __restrict__ fxi,
                                               const float* __restrict__ param,
                                               const float* __restrict__ Cw,
                                               float* __restrict__ out)
{
    __shared__ float2 sa[4096];
    __shared__ float2 sb[4096];
    int bc = blockIdx.x;
    int b = bc >> 6, c = bc & 63;
    int tid = threadIdx.x;
    float cr0 = Cw[b * 3 + 0], cr1 = Cw[b * 3 + 1], cr2 = Cw[b * 3 + 2];
    float ci0 = Cw[192 + b * 3 + 0], ci1 = Cw[192 + b * 3 + 1], ci2 = Cw[192 + b * 3 + 2];
    size_t row = (size_t)bc * FP;
    // param: [N][C][F][2] floats -> as float2: index (n*C + c)*F + f gives (W_R, W_I)
    const float2* W0 = (const float2*)param + (size_t)(0 * 64 + c) * FF;
    const float2* W1 = (const float2*)param + (size_t)(1 * 64 + c) * FF;
    const float2* W2 = (const float2*)param + (size_t)(2 * 64 + c) * FF;

    auto Pf = [&](int f, float& pr, float& pi) {
        float2 w0 = W0[f], w1 = W1[f], w2 = W2[f];
        float kr = cr0 * w0.x + cr1 * w1.x + cr2 * w2.x;
        float ki = ci0 * w0.y + ci1 * w1.y + ci2 * w2.y;
        float fr = fxr[row + f], fi = fxi[row + f];
        pr = fr * kr - fi * ki;
        pi = fr * ki + fi * kr;
    };

    for (int it = 0; it < 8; ++it) {
        int k = tid + 256 * it;   // 0..2047
        if (k == 0) {
            float p0r, p0i, pmr, pmi, phr, phi;
            Pf(0, p0r, p0i);      // imag ignored (c2r semantics)
            Pf(M4, pmr, pmi);     // imag ignored
            Pf(2048, phr, phi);
            sa[0]    = make_float2(0.5f * (p0r + pmr), 0.5f * (p0r - pmr));
            sa[2048] = make_float2(phr, -phi);   // Z[M/2] = conj(P[M/2])
        } else {
            float pkr, pki, pmr, pmi;
            Pf(k, pkr, pki);
            Pf(M4 - k, pmr, pmi);
            float zer = 0.5f * (pkr + pmr);
            float zei = 0.5f * (pki - pmi);
            float dr  = 0.5f * (pkr - pmr);
            float di  = 0.5f * (pki + pmi);
            float sp, cp;
            __sincosf(6.283185307179586f * (float)k * (1.0f / 8192.0f), &sp, &cp);
            float zor = dr * cp - di * sp;
            float zoi = dr * sp + di * cp;
            sa[k]      = make_float2(zer - zoi, zei + zor);
            sa[M4 - k] = make_float2(zer + zoi, zor - zei);
        }
    }
    __syncthreads();
    fft4096_sh(sa, sb, tid, -1.0f);

    const float S = 0.02209708691207961f;  // sqrt(8192)/4096
    float2* orow = (float2*)(out + (size_t)bc * LL);
    for (int j = tid; j < 4096; j += 256) {
        float2 z = sa[j];
        orow[j] = make_float2(S * z.x, S * z.y);
    }
}

// ---------------------------------------------------------------------------
extern "C" void kernel_launch(void* const* d_in, const int* in_sizes, int n_in,
                              void* d_out, int out_size, void* d_ws, size_t ws_size,
                              hipStream_t stream)
{
    (void)in_sizes; (void)n_in; (void)out_size; (void)ws_size;
    const float* x   = (const float*)d_in[0];
    const float* prm = (const float*)d_in[1];
    const float* wR1 = (const float*)d_in[2];
    const float* bR1 = (const float*)d_in[3];
    const float* wR2 = (const float*)d_in[4];
    const float* bR2 = (const float*)d_in[5];
    const float* wI1 = (const float*)d_in[6];
    const float* bI1 = (const float*)d_in[7];
    const float* wI2 = (const float*)d_in[8];
    const float* bI2 = (const float*)d_in[9];
    float* out = (float*)d_out;
    float* ws  = (float*)d_ws;

    size_t o = 0;
    float* fxr  = ws + o; o += (size_t)BB * CCH * FP;     // 16.81M floats
    float* fxi  = ws + o; o += (size_t)BB * CCH * FP;     // 16.81M floats
    float* part = ws + o; o += (size_t)2 * 64 * 128 * 33; // 540K floats
    float* e0   = ws + o; o += 2 * 64 * 128;
    float* e1   = ws + o; o += 2 * 64 * 128;
    float* Cw   = ws + o; o += 2 * 64 * 3;

    k_rfft<<<dim3(4096), dim3(256), 0, stream>>>(x, fxr, fxi);
    k_conv1<<<dim3(33, 64, 2), dim3(256), 0, stream>>>(fxr, fxi, wR1, bR1, wI1, bI1,
                                                       part, e0, e1);
    k_head<<<dim3(64, 2), dim3(128), 0, stream>>>(part, e0, e1, wR2, bR2, wI2, bI2, Cw);
    k_irfft<<<dim3(4096), dim3(256), 0, stream>>>(fxr, fxi, prm, Cw, out);
}

// Round 2
// 598.903 us; speedup vs baseline: 1.4833x; 1.4833x over previous
//
#include <hip/hip_runtime.h>
#include <math.h>

// Problem constants
#define BB 64
#define CCH 64
#define LL 8192
#define NN 3
#define FF 4097
#define FP 4104   // padded row stride for spectra (16B-aligned rows)
#define HIDC 128
#define M4 4096
#define NT 65     // number of 64-wide t tiles over F=4097

typedef __attribute__((ext_vector_type(8))) short short8;
typedef __attribute__((ext_vector_type(4))) float floatx4;

__device__ __forceinline__ short f2bf(float v) {
    union { float f; unsigned u; } cv; cv.f = v;
    unsigned r = (cv.u + 0x7fffu + ((cv.u >> 16) & 1u)) >> 16;
    return (short)r;
}

// ---------------------------------------------------------------------------
// Stockham radix-2 complex FFT, length 4096, in LDS. 256 threads.
// dir = +1.0f : forward (e^{-2pi i pk/n});  dir = -1.0f : positive-sign (inverse)
// ---------------------------------------------------------------------------
__device__ __forceinline__ void fft4096_sh(float2* sa, float2* sb, int tid, float dir)
{
    float2* src = sa;
    float2* dst = sb;
    int ncur = 4096;
    for (int st = 0; st < 12; ++st) {
        int s = 1 << st;
        float inv = dir * (-6.283185307179586f) / (float)ncur;
        for (int i = tid; i < 2048; i += 256) {
            int p = i >> st;
            int q = i & (s - 1);
            float ang = inv * (float)p;
            float sw, cw;
            __sincosf(ang, &sw, &cw);
            float2 u = src[i];
            float2 v = src[i + 2048];
            float2 sm = make_float2(u.x + v.x, u.y + v.y);
            float2 df = make_float2(u.x - v.x, u.y - v.y);
            float2 tw = make_float2(df.x * cw - df.y * sw, df.x * sw + df.y * cw);
            int o = q + (p << (st + 1));
            dst[o] = sm;
            dst[o + s] = tw;
        }
        __syncthreads();
        float2* t = src; src = dst; dst = t;
        ncur >>= 1;
    }
}

// ---------------------------------------------------------------------------
// Kernel A: rfft of each (b,c) row, ortho norm. Writes fxr/fxi [B*C][FP].
// ---------------------------------------------------------------------------
__global__ __launch_bounds__(256) void k_rfft(const float* __restrict__ x,
                                              float* __restrict__ fxr,
                                              float* __restrict__ fxi)
{
    __shared__ float2 sa[4096];
    __shared__ float2 sb[4096];
    int bc = blockIdx.x;
    int tid = threadIdx.x;
    const float2* xr = (const float2*)(x + (size_t)bc * LL);
    for (int j = tid; j < 4096; j += 256) sa[j] = xr[j];
    __syncthreads();
    fft4096_sh(sa, sb, tid, 1.0f);

    const float scale = 0.011048543456039806f; // 1/sqrt(8192)
    size_t row = (size_t)bc * FP;
    for (int it = 0; it < 8; ++it) {
        int k = tid + 256 * it;   // 0..2047
        if (k == 0) {
            float2 z0 = sa[0];
            fxr[row + 0]  = (z0.x + z0.y) * scale;
            fxi[row + 0]  = 0.0f;
            fxr[row + M4] = (z0.x - z0.y) * scale;
            fxi[row + M4] = 0.0f;
            float2 zh = sa[2048];           // X[M/2] = conj(Z[M/2])
            fxr[row + 2048] =  zh.x * scale;
            fxi[row + 2048] = -zh.y * scale;
        } else {
            float2 zk = sa[k];
            float2 zm = sa[M4 - k];
            float er = 0.5f * (zk.x + zm.x);
            float ei = 0.5f * (zk.y - zm.y);
            float dr = 0.5f * (zk.x - zm.x);
            float di = 0.5f * (zk.y + zm.y);
            float sp, cp;
            __sincosf(6.283185307179586f * (float)k * (1.0f / 8192.0f), &sp, &cp);
            fxr[row + k] = (er + cp * di - sp * dr) * scale;
            fxi[row + k] = (ei - cp * dr - sp * di) * scale;
            fxr[row + M4 - k] = (er - (cp * di - sp * dr)) * scale;
            fxi[row + M4 - k] = (-ei - (cp * dr + sp * di)) * scale;
        }
    }
}

// ---------------------------------------------------------------------------
// Prep: pack conv1 weights to bf16 in MFMA K-order k = kappa*64 + c.
// Wp[enc][h][k] with k-step s (32 wide): kappa = s>>1, c = (s&1)*32 + (k&31)
// ---------------------------------------------------------------------------
__global__ __launch_bounds__(256) void k_pack(const float* __restrict__ wR1,
                                              const float* __restrict__ wI1,
                                              short* __restrict__ Wp)
{
    int idx = blockIdx.x * 256 + threadIdx.x;
    if (idx >= 2 * 128 * 192) return;
    int enc = idx / (128 * 192);
    int rem = idx - enc * (128 * 192);
    int h = rem / 192;
    int k = rem - h * 192;
    int s = k >> 5;
    int j = k & 31;
    int kap = s >> 1;
    int c = (s & 1) * 32 + j;
    const float* w = enc ? wI1 : wR1;
    Wp[idx] = f2bf(w[(h * 64 + c) * 3 + kap]);
}

// ---------------------------------------------------------------------------
// Kernel B1 (MFMA): conv1 (C=64 -> HID=128, k=3, SAME) + bias + SELU +
// per-tile partial sums over t + endpoint captures.
// grid: (65 t-tiles, 64 b, 2 enc); 256 threads = 4 waves.
// Wave w computes h in [w*32, w*32+32), t in [t0, t0+64): 2x4 tiles of 16x16,
// K = 192 in 6 steps of 32 (step s: kappa=s>>1, c0=(s&1)*32).
// ---------------------------------------------------------------------------
__global__ __launch_bounds__(256) void k_conv_mfma(const float* __restrict__ fxr,
                                                   const float* __restrict__ fxi,
                                                   const short* __restrict__ Wp,
                                                   const float* __restrict__ bR1,
                                                   const float* __restrict__ bI1,
                                                   float* __restrict__ part,
                                                   float* __restrict__ e0,
                                                   float* __restrict__ e1)
{
    __shared__ short Xt[66 * 72];   // [tt][c], stride 72 breaks bank conflicts
    int tile = blockIdx.x;   // 0..64
    int b    = blockIdx.y;
    int enc  = blockIdx.z;
    const float* src = enc ? fxi : fxr;
    const float* b1  = enc ? bI1 : bR1;
    int tid = threadIdx.x;
    int t0 = tile * 64;

    // Stage X tile [c][t0-1 .. t0+64] -> Xt[tt][c] as bf16 (zero-padded)
    const float* xb = src + (size_t)b * 64 * FP;
    for (int ii = tid; ii < 66 * 64; ii += 256) {
        int c  = ii / 66;
        int tt = ii - c * 66;
        int tg = t0 - 1 + tt;
        float v = (tg >= 0 && tg < FF) ? xb[(size_t)c * FP + tg] : 0.0f;
        Xt[tt * 72 + c] = f2bf(v);
    }
    __syncthreads();

    int w = tid >> 6;
    int lane = tid & 63;
    int n = lane & 15;       // A-row m / B-col n / C-col n
    int q = lane >> 4;       // k-quad
    int h0 = w * 32;

    // Preload A fragments: lane (m=n, q) holds Wp[h0+hb*16+n][s*32 + q*8 .. +8]
    short8 afrag[2][6];
    const short* wbase = Wp + (size_t)enc * 128 * 192;
#pragma unroll
    for (int hb = 0; hb < 2; ++hb)
#pragma unroll
        for (int s = 0; s < 6; ++s)
            afrag[hb][s] = *(const short8*)(wbase + (h0 + hb * 16 + n) * 192 + s * 32 + q * 8);

    floatx4 acc[2][4] = {};
#pragma unroll
    for (int s = 0; s < 6; ++s) {
        int kap = s >> 1;
        int c0 = (s & 1) * 32;
#pragma unroll
        for (int tb = 0; tb < 4; ++tb) {
            // B[k][n] = X[c0+q*8+j][t0 + tb*16 + n + kap - 1] = Xt[tb*16+n+kap][c0+q*8+j]
            short8 bfrag = *(const short8*)(&Xt[(tb * 16 + n + kap) * 72 + c0 + q * 8]);
            acc[0][tb] = __builtin_amdgcn_mfma_f32_16x16x32_bf16(afrag[0][s], bfrag, acc[0][tb], 0, 0, 0);
            acc[1][tb] = __builtin_amdgcn_mfma_f32_16x16x32_bf16(afrag[1][s], bfrag, acc[1][tb], 0, 0, 0);
        }
    }

    // Epilogue: bias + SELU + mask + reduce over t (lane&15) per h
    const float SELU_S = 1.0507009873554805f;
    const float SELU_A = 1.6732632423543772f;
    int ebase = (enc * 64 + b) * 128;
#pragma unroll
    for (int hb = 0; hb < 2; ++hb) {
        float hsum[4] = {0.0f, 0.0f, 0.0f, 0.0f};
#pragma unroll
        for (int tb = 0; tb < 4; ++tb) {
            int t = t0 + tb * 16 + n;
            bool valid = (t < FF);
#pragma unroll
            for (int r = 0; r < 4; ++r) {
                int h = h0 + hb * 16 + q * 4 + r;
                float val = acc[hb][tb][r] + b1[h];
                float y = SELU_S * (val > 0.0f ? val : SELU_A * (__expf(val) - 1.0f));
                y = valid ? y : 0.0f;
                hsum[r] += y;
                if (valid && t == 0)      e0[ebase + h] = y;
                if (valid && t == FF - 1) e1[ebase + h] = y;
            }
        }
#pragma unroll
        for (int off = 1; off < 16; off <<= 1) {
#pragma unroll
            for (int r = 0; r < 4; ++r)
                hsum[r] += __shfl_xor(hsum[r], off, 64);
        }
        if (n == 0) {
#pragma unroll
            for (int r = 0; r < 4; ++r) {
                int h = h0 + hb * 16 + q * 4 + r;
                part[((size_t)(enc * 64 + b) * 128 + h) * NT + tile] = hsum[r];
            }
        }
    }
}

// ---------------------------------------------------------------------------
// Kernel B2: conv2 (fused with mean via endpoint algebra) + bias + softmax
// ---------------------------------------------------------------------------
__global__ __launch_bounds__(128) void k_head(const float* __restrict__ part,
                                              const float* __restrict__ e0,
                                              const float* __restrict__ e1,
                                              const float* __restrict__ wR2,
                                              const float* __restrict__ bR2,
                                              const float* __restrict__ wI2,
                                              const float* __restrict__ bI2,
                                              float* __restrict__ Cw)
{
    __shared__ float red[3][128];
    int b   = blockIdx.x;
    int enc = blockIdx.y;
    const float* w2 = enc ? wI2 : wR2;
    const float* b2 = enc ? bI2 : bR2;
    int h = threadIdx.x;
    size_t pb = ((size_t)(enc * 64 + b) * 128 + h) * NT;
    float T = 0.0f;
    for (int t = 0; t < NT; ++t) T += part[pb + t];
    float e0v = e0[(enc * 64 + b) * 128 + h];
    float e1v = e1[(enc * 64 + b) * 128 + h];
#pragma unroll
    for (int n = 0; n < 3; ++n) {
        const float* wp = w2 + (n * 128 + h) * 3;
        red[n][h] = wp[0] * (T - e1v) + wp[1] * T + wp[2] * (T - e0v);
    }
    __syncthreads();
    if (h == 0) {
        float lg[3];
        for (int n = 0; n < 3; ++n) {
            float s = 0.0f;
            for (int q = 0; q < 128; ++q) s += red[n][q];
            lg[n] = b2[n] + s / 4097.0f;
        }
        float mx = fmaxf(lg[0], fmaxf(lg[1], lg[2]));
        float ex0 = __expf(lg[0] - mx);
        float ex1 = __expf(lg[1] - mx);
        float ex2 = __expf(lg[2] - mx);
        float den = ex0 + ex1 + ex2;
        Cw[(enc * 64 + b) * 3 + 0] = ex0 / den;
        Cw[(enc * 64 + b) * 3 + 1] = ex1 / den;
        Cw[(enc * 64 + b) * 3 + 2] = ex2 / den;
    }
}

// ---------------------------------------------------------------------------
// Kernel C: P = fx * Kf, then irfft via length-4096 positive-sign FFT.
// ---------------------------------------------------------------------------
__global__ __launch_bounds__(256) void k_irfft(const float* __restrict__ fxr,
                                               const float* __restrict__ fxi,
                                               const float* __restrict__ param,
                                               const float* __restrict__ Cw,
                                               float* __restrict__ out)
{
    __shared__ float2 sa[4096];
    __shared__ float2 sb[4096];
    int bc = blockIdx.x;
    int b = bc >> 6, c = bc & 63;
    int tid = threadIdx.x;
    float cr0 = Cw[b * 3 + 0], cr1 = Cw[b * 3 + 1], cr2 = Cw[b * 3 + 2];
    float ci0 = Cw[192 + b * 3 + 0], ci1 = Cw[192 + b * 3 + 1], ci2 = Cw[192 + b * 3 + 2];
    size_t row = (size_t)bc * FP;
    const float2* W0 = (const float2*)param + (size_t)(0 * 64 + c) * FF;
    const float2* W1 = (const float2*)param + (size_t)(1 * 64 + c) * FF;
    const float2* W2 = (const float2*)param + (size_t)(2 * 64 + c) * FF;

    auto Pf = [&](int f, float& pr, float& pi) {
        float2 w0 = W0[f], w1 = W1[f], w2 = W2[f];
        float kr = cr0 * w0.x + cr1 * w1.x + cr2 * w2.x;
        float ki = ci0 * w0.y + ci1 * w1.y + ci2 * w2.y;
        float fr = fxr[row + f], fi = fxi[row + f];
        pr = fr * kr - fi * ki;
        pi = fr * ki + fi * kr;
    };

    for (int it = 0; it < 8; ++it) {
        int k = tid + 256 * it;
        if (k == 0) {
            float p0r, p0i, pmr, pmi, phr, phi;
            Pf(0, p0r, p0i);
            Pf(M4, pmr, pmi);
            Pf(2048, phr, phi);
            sa[0]    = make_float2(0.5f * (p0r + pmr), 0.5f * (p0r - pmr));
            sa[2048] = make_float2(phr, -phi);
        } else {
            float pkr, pki, pmr, pmi;
            Pf(k, pkr, pki);
            Pf(M4 - k, pmr, pmi);
            float zer = 0.5f * (pkr + pmr);
            float zei = 0.5f * (pki - pmi);
            float dr  = 0.5f * (pkr - pmr);
            float di  = 0.5f * (pki + pmi);
            float sp, cp;
            __sincosf(6.283185307179586f * (float)k * (1.0f / 8192.0f), &sp, &cp);
            float zor = dr * cp - di * sp;
            float zoi = dr * sp + di * cp;
            sa[k]      = make_float2(zer - zoi, zei + zor);
            sa[M4 - k] = make_float2(zer + zoi, zor - zei);
        }
    }
    __syncthreads();
    fft4096_sh(sa, sb, tid, -1.0f);

    const float S = 0.02209708691207961f;  // sqrt(8192)/4096
    float2* orow = (float2*)(out + (size_t)bc * LL);
    for (int j = tid; j < 4096; j += 256) {
        float2 z = sa[j];
        orow[j] = make_float2(S * z.x, S * z.y);
    }
}

// ---------------------------------------------------------------------------
extern "C" void kernel_launch(void* const* d_in, const int* in_sizes, int n_in,
                              void* d_out, int out_size, void* d_ws, size_t ws_size,
                              hipStream_t stream)
{
    (void)in_sizes; (void)n_in; (void)out_size; (void)ws_size;
    const float* x   = (const float*)d_in[0];
    const float* prm = (const float*)d_in[1];
    const float* wR1 = (const float*)d_in[2];
    const float* bR1 = (const float*)d_in[3];
    const float* wR2 = (const float*)d_in[4];
    const float* bR2 = (const float*)d_in[5];
    const float* wI1 = (const float*)d_in[6];
    const float* bI1 = (const float*)d_in[7];
    const float* wI2 = (const float*)d_in[8];
    const float* bI2 = (const float*)d_in[9];
    float* out = (float*)d_out;
    float* ws  = (float*)d_ws;

    size_t o = 0;
    float* fxr  = ws + o; o += (size_t)BB * CCH * FP;      // 16.81M floats
    float* fxi  = ws + o; o += (size_t)BB * CCH * FP;      // 16.81M floats
    float* part = ws + o; o += (size_t)2 * 64 * 128 * NT;  // 1.06M floats
    float* e0   = ws + o; o += 2 * 64 * 128;
    float* e1   = ws + o; o += 2 * 64 * 128;
    float* Cw   = ws + o; o += 2 * 64 * 4;
    short* Wp   = (short*)(ws + o); o += (size_t)2 * 128 * 192 / 2;  // bf16 packed weights

    k_rfft<<<dim3(4096), dim3(256), 0, stream>>>(x, fxr, fxi);
    k_pack<<<dim3((2 * 128 * 192 + 255) / 256), dim3(256), 0, stream>>>(wR1, wI1, Wp);
    k_conv_mfma<<<dim3(NT, 64, 2), dim3(256), 0, stream>>>(fxr, fxi, Wp, bR1, bI1,
                                                           part, e0, e1);
    k_head<<<dim3(64, 2), dim3(128), 0, stream>>>(part, e0, e1, wR2, bR2, wI2, bI2, Cw);
    k_irfft<<<dim3(4096), dim3(256), 0, stream>>>(fxr, fxi, prm, Cw, out);
}

// Round 3
// 418.977 us; speedup vs baseline: 2.1204x; 1.4294x over previous
//
#include <hip/hip_runtime.h>
#include <math.h>

// Problem constants
#define BB 64
#define CCH 64
#define LL 8192
#define FF 4097
#define FP 4104   // padded row stride for spectra
#define M4 4096
#define NT 65     // 64-wide t tiles over F=4097

typedef __attribute__((ext_vector_type(8))) short short8;
typedef __attribute__((ext_vector_type(4))) float floatx4;

__device__ __forceinline__ short f2bf(float v) {
    union { float f; unsigned u; } cv; cv.f = v;
    unsigned r = (cv.u + 0x7fffu + ((cv.u >> 16) & 1u)) >> 16;
    return (short)r;
}

// ---------------- complex helpers ----------------
__device__ __forceinline__ float2 cadd(float2 a, float2 b){ return make_float2(a.x+b.x, a.y+b.y); }
__device__ __forceinline__ float2 csub(float2 a, float2 b){ return make_float2(a.x-b.x, a.y-b.y); }
__device__ __forceinline__ float2 cmul(float2 a, float2 b){ return make_float2(a.x*b.x-a.y*b.y, a.x*b.y+a.y*b.x); }
template<int SIGN> __device__ __forceinline__ float2 roti(float2 a){
    return (SIGN < 0) ? make_float2(a.y, -a.x) : make_float2(-a.y, a.x);
}
template<int SIGN>
__device__ __forceinline__ void dft4(float2& a, float2& b, float2& c, float2& d){
    float2 t0 = cadd(a,c), t1 = csub(a,c), t2 = cadd(b,d), t3 = roti<SIGN>(csub(b,d));
    a = cadd(t0,t2); b = cadd(t1,t3); c = csub(t0,t2); d = csub(t1,t3);
}

// DFT-16, natural order in and out, fully unrolled, constant twiddles.
// SIGN=-1: X[k] = sum_n v[n] e^{-2pi i nk/16};  SIGN=+1: positive sign.
template<int SIGN>
__device__ __forceinline__ void dft16(float2 v[16]){
    const float C1 = 0.9238795325112867f, S1 = 0.3826834323650898f, R2 = 0.7071067811865476f;
    const float sg = (SIGN < 0) ? -1.0f : 1.0f;
#pragma unroll
    for (int n1 = 0; n1 < 4; ++n1) dft4<SIGN>(v[n1], v[n1+4], v[n1+8], v[n1+12]);
    // twiddle at v[n1 + 4*k2] *= W16^{SIGN*n1*k2}
    const float2 W1 = make_float2( C1, sg*S1);
    const float2 W2 = make_float2( R2, sg*R2);
    const float2 W3 = make_float2( S1, sg*C1);
    const float2 W6 = make_float2(-R2, sg*R2);
    const float2 W9 = make_float2(-C1, -sg*S1);
    v[5]  = cmul(v[5],  W1); v[6]  = cmul(v[6],  W2); v[7]  = cmul(v[7],  W3);
    v[9]  = cmul(v[9],  W2); v[10] = roti<SIGN>(v[10]); v[11] = cmul(v[11], W6);
    v[13] = cmul(v[13], W3); v[14] = cmul(v[14], W6); v[15] = cmul(v[15], W9);
#pragma unroll
    for (int k2 = 0; k2 < 4; ++k2) dft4<SIGN>(v[4*k2+0], v[4*k2+1], v[4*k2+2], v[4*k2+3]);
    // X[k2 + 4*k1] sits at v[4*k2 + k1] -> permute to natural order (reg renaming)
    float2 t[16];
#pragma unroll
    for (int k = 0; k < 16; ++k) t[k] = v[4*(k & 3) + (k >> 2)];
#pragma unroll
    for (int k = 0; k < 16; ++k) v[k] = t[k];
}

// v[j] *= w^j, w = e^{i*ang}
__device__ __forceinline__ void twiddle_pow(float2 v[16], float ang){
    float s, c; __sincosf(ang, &s, &c);
    float2 w = make_float2(c, s), t = w;
    v[1] = cmul(v[1], t);
#pragma unroll
    for (int j = 2; j < 16; ++j){ t = cmul(t, w); v[j] = cmul(v[j], t); }
}

// ---------------------------------------------------------------------------
// Four-step FFT of length 4096 (16x16x16), 256 threads, 16 elems/thread.
// In:  v[j] = z[tid + 256*j].  Out: v[k1] = Z[tid + 256*k1] (natural order).
// lds must hold 4352 float2. Ends with a barrier (lds reusable after).
// ---------------------------------------------------------------------------
template<int SIGN>
__device__ __forceinline__ void fft4096_regs(float2 v[16], float2* lds, int tid){
    const float TWO_PI = 6.283185307179586f;
    const float sg = (SIGN < 0) ? -1.0f : 1.0f;
    int n1 = tid & 15, hi = tid >> 4;
    // round 1: DFT over n2b (stride 256), twiddle W256^{n2a*k2}
    dft16<SIGN>(v);
    twiddle_pow(v, sg * TWO_PI * (float)hi * (1.0f/256.0f));
#pragma unroll
    for (int j = 0; j < 16; ++j) lds[tid + 272*j] = v[j];      // (n1,n2a,k2)->n1+16*n2a+272*k2
    __syncthreads();
#pragma unroll
    for (int j = 0; j < 16; ++j) v[j] = lds[n1 + 16*j + 272*hi]; // read across n2a; hi=k2
    __syncthreads();
    // round 2: DFT over n2a
    dft16<SIGN>(v);
#pragma unroll
    for (int j = 0; j < 16; ++j) lds[(j*16 + hi)*17 + n1] = v[j]; // (k1*16+k2)*17 + n1
    __syncthreads();
#pragma unroll
    for (int j = 0; j < 16; ++j) v[j] = lds[tid*17 + j];          // thread tid == level-A k2
    // round 3: twiddle W4096^{n1*k2}, DFT over n1
    twiddle_pow(v, sg * TWO_PI * (float)tid * (1.0f/4096.0f));
    dft16<SIGN>(v);
    __syncthreads();   // lds free for caller reuse
}

#define COSJ_INIT { 1.0f, 0.980785280403230f, 0.923879532511287f, 0.831469612302545f, \
    0.707106781186548f, 0.555570233019602f, 0.382683432365090f, 0.195090322016128f, \
    0.0f, -0.195090322016128f, -0.382683432365090f, -0.555570233019602f, \
    -0.707106781186548f, -0.831469612302545f, -0.923879532511287f, -0.980785280403230f }
#define SINJ_INIT { 0.0f, 0.195090322016128f, 0.382683432365090f, 0.555570233019602f, \
    0.707106781186548f, 0.831469612302545f, 0.923879532511287f, 0.980785280403230f, \
    1.0f, 0.980785280403230f, 0.923879532511287f, 0.831469612302545f, \
    0.707106781186548f, 0.555570233019602f, 0.382683432365090f, 0.195090322016128f }

// ---------------------------------------------------------------------------
// Kernel A: rfft of each (b,c) row, ortho norm.
// ---------------------------------------------------------------------------
__global__ __launch_bounds__(256, 4) void k_rfft(const float* __restrict__ x,
                                                 float* __restrict__ fxr,
                                                 float* __restrict__ fxi)
{
    __shared__ float2 lds[4352];
    int bc = blockIdx.x, tid = threadIdx.x;
    const float2* xr = (const float2*)(x + (size_t)bc * LL);
    float2 v[16];
#pragma unroll
    for (int j = 0; j < 16; ++j) v[j] = xr[tid + 256*j];
    fft4096_regs<-1>(v, lds, tid);
#pragma unroll
    for (int j = 0; j < 16; ++j) lds[tid + 256*j] = v[j];   // Z plain
    __syncthreads();

    const float scale = 0.011048543456039806f; // 1/sqrt(8192)
    const float COSJ[16] = COSJ_INIT;
    const float SINJ[16] = SINJ_INIT;
    size_t row = (size_t)bc * FP;
    float sA, cA; __sincosf(3.14159265358979f * (float)tid * (1.0f/4096.0f), &sA, &cA);
#pragma unroll
    for (int j = 0; j < 16; ++j){
        int k = tid + 256*j;
        if (k == 0){
            float2 z0 = lds[0];
            fxr[row + 0]  = (z0.x + z0.y) * scale; fxi[row + 0]  = 0.0f;
            fxr[row + M4] = (z0.x - z0.y) * scale; fxi[row + M4] = 0.0f;
        } else {
            float2 zk = lds[k], zm = lds[(4096 - k) & 4095];
            float er = 0.5f*(zk.x + zm.x), ei = 0.5f*(zk.y - zm.y);
            float dr = 0.5f*(zk.x - zm.x), di = 0.5f*(zk.y + zm.y);
            float cp = cA*COSJ[j] - sA*SINJ[j];
            float sp = sA*COSJ[j] + cA*SINJ[j];
            fxr[row + k] = (er + cp*di - sp*dr) * scale;
            fxi[row + k] = (ei - cp*dr - sp*di) * scale;
        }
    }
}

// ---------------------------------------------------------------------------
// Prep: pack conv1 weights to bf16 in MFMA K-order.
// ---------------------------------------------------------------------------
__global__ __launch_bounds__(256) void k_pack(const float* __restrict__ wR1,
                                              const float* __restrict__ wI1,
                                              short* __restrict__ Wp)
{
    int idx = blockIdx.x * 256 + threadIdx.x;
    if (idx >= 2 * 128 * 192) return;
    int enc = idx / (128 * 192);
    int rem = idx - enc * (128 * 192);
    int h = rem / 192;
    int k = rem - h * 192;
    int s = k >> 5;
    int j = k & 31;
    int kap = s >> 1;
    int c = (s & 1) * 32 + j;
    const float* w = enc ? wI1 : wR1;
    Wp[idx] = f2bf(w[(h * 64 + c) * 3 + kap]);
}

// ---------------------------------------------------------------------------
// Kernel B1 (MFMA): conv1 + bias + SELU + partial sums + endpoints.
// ---------------------------------------------------------------------------
__global__ __launch_bounds__(256) void k_conv_mfma(const float* __restrict__ fxr,
                                                   const float* __restrict__ fxi,
                                                   const short* __restrict__ Wp,
                                                   const float* __restrict__ bR1,
                                                   const float* __restrict__ bI1,
                                                   float* __restrict__ part,
                                                   float* __restrict__ e0,
                                                   float* __restrict__ e1)
{
    __shared__ short Xt[66 * 72];
    int tile = blockIdx.x;
    int b    = blockIdx.y;
    int enc  = blockIdx.z;
    const float* src = enc ? fxi : fxr;
    const float* b1  = enc ? bI1 : bR1;
    int tid = threadIdx.x;
    int t0 = tile * 64;

    const float* xb = src + (size_t)b * 64 * FP;
    for (int ii = tid; ii < 66 * 64; ii += 256) {
        int c  = ii / 66;
        int tt = ii - c * 66;
        int tg = t0 - 1 + tt;
        float v = (tg >= 0 && tg < FF) ? xb[(size_t)c * FP + tg] : 0.0f;
        Xt[tt * 72 + c] = f2bf(v);
    }
    __syncthreads();

    int w = tid >> 6;
    int lane = tid & 63;
    int n = lane & 15;
    int q = lane >> 4;
    int h0 = w * 32;

    short8 afrag[2][6];
    const short* wbase = Wp + (size_t)enc * 128 * 192;
#pragma unroll
    for (int hb = 0; hb < 2; ++hb)
#pragma unroll
        for (int s = 0; s < 6; ++s)
            afrag[hb][s] = *(const short8*)(wbase + (h0 + hb * 16 + n) * 192 + s * 32 + q * 8);

    floatx4 acc[2][4] = {};
#pragma unroll
    for (int s = 0; s < 6; ++s) {
        int kap = s >> 1;
        int c0 = (s & 1) * 32;
#pragma unroll
        for (int tb = 0; tb < 4; ++tb) {
            short8 bfrag = *(const short8*)(&Xt[(tb * 16 + n + kap) * 72 + c0 + q * 8]);
            acc[0][tb] = __builtin_amdgcn_mfma_f32_16x16x32_bf16(afrag[0][s], bfrag, acc[0][tb], 0, 0, 0);
            acc[1][tb] = __builtin_amdgcn_mfma_f32_16x16x32_bf16(afrag[1][s], bfrag, acc[1][tb], 0, 0, 0);
        }
    }

    const float SELU_S = 1.0507009873554805f;
    const float SELU_A = 1.6732632423543772f;
    int ebase = (enc * 64 + b) * 128;
#pragma unroll
    for (int hb = 0; hb < 2; ++hb) {
        float hsum[4] = {0.0f, 0.0f, 0.0f, 0.0f};
#pragma unroll
        for (int tb = 0; tb < 4; ++tb) {
            int t = t0 + tb * 16 + n;
            bool valid = (t < FF);
#pragma unroll
            for (int r = 0; r < 4; ++r) {
                int h = h0 + hb * 16 + q * 4 + r;
                float val = acc[hb][tb][r] + b1[h];
                float y = SELU_S * (val > 0.0f ? val : SELU_A * (__expf(val) - 1.0f));
                y = valid ? y : 0.0f;
                hsum[r] += y;
                if (valid && t == 0)      e0[ebase + h] = y;
                if (valid && t == FF - 1) e1[ebase + h] = y;
            }
        }
#pragma unroll
        for (int off = 1; off < 16; off <<= 1) {
#pragma unroll
            for (int r = 0; r < 4; ++r)
                hsum[r] += __shfl_xor(hsum[r], off, 64);
        }
        if (n == 0) {
#pragma unroll
            for (int r = 0; r < 4; ++r) {
                int h = h0 + hb * 16 + q * 4 + r;
                part[((size_t)(enc * 64 + b) * 128 + h) * NT + tile] = hsum[r];
            }
        }
    }
}

// ---------------------------------------------------------------------------
// Kernel B2: conv2 (mean via endpoint algebra) + bias + softmax
// ---------------------------------------------------------------------------
__global__ __launch_bounds__(128) void k_head(const float* __restrict__ part,
                                              const float* __restrict__ e0,
                                              const float* __restrict__ e1,
                                              const float* __restrict__ wR2,
                                              const float* __restrict__ bR2,
                                              const float* __restrict__ wI2,
                                              const float* __restrict__ bI2,
                                              float* __restrict__ Cw)
{
    __shared__ float red[3][128];
    int b   = blockIdx.x;
    int enc = blockIdx.y;
    const float* w2 = enc ? wI2 : wR2;
    const float* b2 = enc ? bI2 : bR2;
    int h = threadIdx.x;
    size_t pb = ((size_t)(enc * 64 + b) * 128 + h) * NT;
    float T = 0.0f;
    for (int t = 0; t < NT; ++t) T += part[pb + t];
    float e0v = e0[(enc * 64 + b) * 128 + h];
    float e1v = e1[(enc * 64 + b) * 128 + h];
#pragma unroll
    for (int n = 0; n < 3; ++n) {
        const float* wp = w2 + (n * 128 + h) * 3;
        red[n][h] = wp[0] * (T - e1v) + wp[1] * T + wp[2] * (T - e0v);
    }
    __syncthreads();
    if (h == 0) {
        float lg[3];
        for (int n = 0; n < 3; ++n) {
            float s = 0.0f;
            for (int q = 0; q < 128; ++q) s += red[n][q];
            lg[n] = b2[n] + s / 4097.0f;
        }
        float mx = fmaxf(lg[0], fmaxf(lg[1], lg[2]));
        float ex0 = __expf(lg[0] - mx);
        float ex1 = __expf(lg[1] - mx);
        float ex2 = __expf(lg[2] - mx);
        float den = ex0 + ex1 + ex2;
        Cw[(enc * 64 + b) * 3 + 0] = ex0 / den;
        Cw[(enc * 64 + b) * 3 + 1] = ex1 / den;
        Cw[(enc * 64 + b) * 3 + 2] = ex2 / den;
    }
}

// ---------------------------------------------------------------------------
// Kernel C: P = fx*Kf -> inverse FFT (register radix-16^3) -> out row.
// ---------------------------------------------------------------------------
__global__ __launch_bounds__(256, 4) void k_irfft(const float* __restrict__ fxr,
                                                  const float* __restrict__ fxi,
                                                  const float* __restrict__ param,
                                                  const float* __restrict__ Cw,
                                                  float* __restrict__ out)
{
    __shared__ float2 lds[4352];
    int bc = blockIdx.x, b = bc >> 6, c = bc & 63, tid = threadIdx.x;
    float cr0 = Cw[b*3+0], cr1 = Cw[b*3+1], cr2 = Cw[b*3+2];
    float ci0 = Cw[192 + b*3+0], ci1 = Cw[192 + b*3+1], ci2 = Cw[192 + b*3+2];
    size_t row = (size_t)bc * FP;
    const float2* W0 = (const float2*)param + (size_t)(0*64 + c) * FF;
    const float2* W1 = (const float2*)param + (size_t)(1*64 + c) * FF;
    const float2* W2 = (const float2*)param + (size_t)(2*64 + c) * FF;

    // stage P[f] = fx[f] * Kf[f] into LDS, f = 0..4096
    for (int f = tid; f <= 4096; f += 256) {
        float2 w0 = W0[f], w1 = W1[f], w2 = W2[f];
        float kr = cr0*w0.x + cr1*w1.x + cr2*w2.x;
        float ki = ci0*w0.y + ci1*w1.y + ci2*w2.y;
        float fr = fxr[row + f], fi = fxi[row + f];
        lds[f] = make_float2(fr*kr - fi*ki, fr*ki + fi*kr);
    }
    __syncthreads();

    // build packed spectrum Z[m] in registers (c2r semantics: imag of 0/Nyq ignored)
    const float COSJ[16] = COSJ_INIT;
    const float SINJ[16] = SINJ_INIT;
    float2 v[16];
    float sA, cA; __sincosf(3.14159265358979f * (float)tid * (1.0f/4096.0f), &sA, &cA);
#pragma unroll
    for (int j = 0; j < 16; ++j) {
        int m = tid + 256*j;
        if (m == 0) {
            float p0 = lds[0].x, pn = lds[4096].x;
            v[j] = make_float2(0.5f*(p0 + pn), 0.5f*(p0 - pn));
        } else {
            float2 p = lds[m], q = lds[4096 - m];
            float er = 0.5f*(p.x + q.x), ei = 0.5f*(p.y - q.y);
            float dr = 0.5f*(p.x - q.x), di = 0.5f*(p.y + q.y);
            float cp = cA*COSJ[j] - sA*SINJ[j];
            float sp = sA*COSJ[j] + cA*SINJ[j];
            float zor = dr*cp - di*sp;
            float zoi = dr*sp + di*cp;
            v[j] = make_float2(er - zoi, ei + zor);
        }
    }
    __syncthreads();
    fft4096_regs<1>(v, lds, tid);

    const float S = 0.02209708691207961f;  // sqrt(8192)/4096
    float2* orow = (float2*)(out + (size_t)bc * LL);
#pragma unroll
    for (int j = 0; j < 16; ++j) {
        float2 z = v[j];
        orow[tid + 256*j] = make_float2(S*z.x, S*z.y);
    }
}

// ---------------------------------------------------------------------------
extern "C" void kernel_launch(void* const* d_in, const int* in_sizes, int n_in,
                              void* d_out, int out_size, void* d_ws, size_t ws_size,
                              hipStream_t stream)
{
    (void)in_sizes; (void)n_in; (void)out_size; (void)ws_size;
    const float* x   = (const float*)d_in[0];
    const float* prm = (const float*)d_in[1];
    const float* wR1 = (const float*)d_in[2];
    const float* bR1 = (const float*)d_in[3];
    const float* wR2 = (const float*)d_in[4];
    const float* bR2 = (const float*)d_in[5];
    const float* wI1 = (const float*)d_in[6];
    const float* bI1 = (const float*)d_in[7];
    const float* wI2 = (const float*)d_in[8];
    const float* bI2 = (const float*)d_in[9];
    float* out = (float*)d_out;
    float* ws  = (float*)d_ws;

    size_t o = 0;
    float* fxr  = ws + o; o += (size_t)BB * CCH * FP;
    float* fxi  = ws + o; o += (size_t)BB * CCH * FP;
    float* part = ws + o; o += (size_t)2 * 64 * 128 * NT;
    float* e0   = ws + o; o += 2 * 64 * 128;
    float* e1   = ws + o; o += 2 * 64 * 128;
    float* Cw   = ws + o; o += 2 * 64 * 4;
    short* Wp   = (short*)(ws + o); o += (size_t)2 * 128 * 192 / 2;

    k_rfft<<<dim3(4096), dim3(256), 0, stream>>>(x, fxr, fxi);
    k_pack<<<dim3((2 * 128 * 192 + 255) / 256), dim3(256), 0, stream>>>(wR1, wI1, Wp);
    k_conv_mfma<<<dim3(NT, 64, 2), dim3(256), 0, stream>>>(fxr, fxi, Wp, bR1, bI1,
                                                           part, e0, e1);
    k_head<<<dim3(64, 2), dim3(128), 0, stream>>>(part, e0, e1, wR2, bR2, wI2, bI2, Cw);
    k_irfft<<<dim3(4096), dim3(256), 0, stream>>>(fxr, fxi, prm, Cw, out);
}